// Round 2
// baseline (139.999 us; speedup 1.0000x reference)
//
#include <hip/hip_runtime.h>
#include <math.h>

typedef unsigned long long u64;
typedef unsigned int u32;

#define NB 256       // batch
#define NQ 1000      // queries
#define NC 80        // classes
#define QC 80000     // NQ*NC per row
#define TOPK 300
#define CAP 2048     // per-row candidate capacity (power of 2 = bitonic size)
#define SEGS 8       // collect blocks per row
#define SEGQ (QC / 4 / SEGS)   // float4s per collect block = 2500
#define CAPB 512     // per-collect-block LDS candidate capacity (~228 expected)
#define CTHREADS 256
#define STHREADS 1024

// ws layout: [0, NB) u32 per-row counters; candidate buffer at byte 4096,
// NB rows x CAP u64 keys = 4 MB. (ws_size is far larger than this.)
#define WS_BUF_OFF 4096

// key = (positive-float bits << 32) | (0xFFFFFFFF - flat_idx)
// -> descending sort gives jax.lax.top_k order (ties: lower index first).

__global__ __launch_bounds__(CTHREADS) void collect_kernel(
    const float* __restrict__ logits, u32* __restrict__ ctr,
    u64* __restrict__ cand) {
  const int row = blockIdx.x >> 3;
  const int seg = blockIdx.x & 7;
  const int tid = threadIdx.x;

  __shared__ u64 s_buf[CAPB];
  __shared__ int s_cnt;
  __shared__ int s_base;

  if (tid == 0) s_cnt = 0;
  __syncthreads();

  const float4* lp = (const float4*)logits + (size_t)row * (QC / 4);
  const float T = 2.0f;
  const int i0 = seg * SEGQ;

  for (int i = i0 + tid; i < i0 + SEGQ; i += CTHREADS) {
    float4 v = lp[i];
    float xs[4] = {v.x, v.y, v.z, v.w};
#pragma unroll
    for (int c = 0; c < 4; ++c) {
      float x = xs[c];
      if (x > T) {
        int pos = atomicAdd(&s_cnt, 1);
        if (pos < CAPB) {
          u32 idx = (u32)(4 * i + c);
          s_buf[pos] = ((u64)__float_as_uint(x) << 32) | (u64)(0xFFFFFFFFu - idx);
        }
      }
    }
  }
  __syncthreads();

  if (tid == 0) {
    int n = s_cnt;
    s_base = (int)atomicAdd(&ctr[row], (u32)n);
    if (n > CAPB) atomicAdd(&ctr[row], 1u << 20);  // force fallback: entries lost
  }
  __syncthreads();

  int n = min(s_cnt, CAPB);
  u64* rowbuf = cand + (size_t)row * CAP;
  for (int j = tid; j < n; j += CTHREADS) {
    int dst = s_base + j;
    if (dst < CAP) rowbuf[dst] = s_buf[j];  // if row total > CAP, fallback runs anyway
  }
}

__global__ __launch_bounds__(STHREADS) void sort_emit_kernel(
    const float* __restrict__ logits, const float4* __restrict__ boxes,
    const u32* __restrict__ ctr, const u64* __restrict__ cand,
    float* __restrict__ out) {
  const int row = blockIdx.x;
  const int tid = threadIdx.x;

  __shared__ u64 s_keys[CAP];
  __shared__ int s_cnt;

  int cnt = (int)ctr[row];

  if (cnt >= TOPK && cnt <= CAP) {
    // fast path: candidates already in ws
    const u64* rowbuf = cand + (size_t)row * CAP;
    for (int i = tid; i < cnt; i += STHREADS) s_keys[i] = rowbuf[i];
  } else {
    // fallback (never taken on N(0,1) data): re-collect from logits w/ retry
    const float4* lp = (const float4*)logits + (size_t)row * (QC / 4);
    float T = 2.0f;
    for (int attempt = 0; attempt < 24; ++attempt) {
      __syncthreads();
      if (tid == 0) s_cnt = 0;
      __syncthreads();
      for (int i = tid; i < QC / 4; i += STHREADS) {
        float4 v = lp[i];
        float xs[4] = {v.x, v.y, v.z, v.w};
#pragma unroll
        for (int c = 0; c < 4; ++c) {
          float x = xs[c];
          if (x > T) {
            int pos = atomicAdd(&s_cnt, 1);
            if (pos < CAP) {
              u32 idx = (u32)(4 * i + c);
              s_keys[pos] = ((u64)__float_as_uint(x) << 32) | (u64)(0xFFFFFFFFu - idx);
            }
          }
        }
      }
      __syncthreads();
      cnt = s_cnt;
      if (cnt >= TOPK && cnt <= CAP) break;
      T = (cnt < TOPK) ? (T - 0.9f) : (T + 0.45f);
    }
    if (cnt > CAP) cnt = CAP;
  }

  // pad to CAP (zero keys sort last under descending order)
  for (int i = cnt + tid; i < CAP; i += STHREADS) s_keys[i] = 0ull;
  __syncthreads();

  // bitonic sort, descending: CAP/2 = 1024 compare-exchanges per half-stage,
  // exactly one per thread.
  for (int size = 2; size <= CAP; size <<= 1) {
    for (int stride = size >> 1; stride > 0; stride >>= 1) {
      int i = tid;
      int lo = 2 * i - (i & (stride - 1));
      int hi = lo + stride;
      u64 a = s_keys[lo];
      u64 b = s_keys[hi];
      bool desc = (lo & size) == 0;
      if (desc ? (a < b) : (a > b)) {
        s_keys[lo] = b;
        s_keys[hi] = a;
      }
      __syncthreads();
    }
  }

  if (tid < TOPK) {
    const int k = tid;
    float* labels_out = out;                  // [NB, TOPK]
    float* boxes_out = out + NB * TOPK;       // [NB, TOPK, 4]
    float* scores_out = out + NB * TOPK * 5;  // [NB, TOPK]

    float lab = 0.0f, score = 0.0f;
    float4 bo = make_float4(0.0f, 0.0f, 0.0f, 0.0f);
    if (k < cnt) {
      u64 key = s_keys[k];
      u32 idx = 0xFFFFFFFFu - (u32)(key & 0xFFFFFFFFull);
      float x = __uint_as_float((u32)(key >> 32));
      int q = (int)(idx / NC);
      int c = (int)(idx - (u32)q * NC);
      lab = (float)c;
      score = (float)(1.0 / (1.0 + exp(-(double)x)));  // exact f32 sigmoid
      float4 bb = boxes[(size_t)row * NQ + q];
      float hw = 0.5f * bb.z, hh = 0.5f * bb.w;
      bo.x = bb.x - hw;
      bo.y = bb.y - hh;
      bo.z = bb.x + hw;
      bo.w = bb.y + hh;
    }
    labels_out[row * TOPK + k] = lab;
    scores_out[row * TOPK + k] = score;
    ((float4*)boxes_out)[row * TOPK + k] = bo;
  }
}

extern "C" void kernel_launch(void* const* d_in, const int* in_sizes, int n_in,
                              void* d_out, int out_size, void* d_ws, size_t ws_size,
                              hipStream_t stream) {
  const float* logits = (const float*)d_in[0];
  const float4* boxes = (const float4*)d_in[1];
  float* out = (float*)d_out;

  u32* ctr = (u32*)d_ws;
  u64* cand = (u64*)((char*)d_ws + WS_BUF_OFF);

  hipMemsetAsync(ctr, 0, NB * sizeof(u32), stream);
  collect_kernel<<<NB * SEGS, CTHREADS, 0, stream>>>(logits, ctr, cand);
  sort_emit_kernel<<<NB, STHREADS, 0, stream>>>(logits, boxes, ctr, cand, out);
}

// Round 3
// 131.214 us; speedup vs baseline: 1.0669x; 1.0669x over previous
//
#include <hip/hip_runtime.h>
#include <math.h>

typedef unsigned long long u64;
typedef unsigned int u32;

#define NB 256       // batch
#define NQ 1000      // queries
#define NC 80        // classes
#define QC 80000     // NQ*NC per row
#define TOPK 300
#define CAP 1024     // candidate capacity = bitonic size (power of 2)
#define NTHREADS 1024

// T=2.42: P(N(0,1) > 2.42) ~ 0.00776 -> ~620 +/- 25 candidates of 80000 per
// row. [300, 1024] is [-12.9s, +16s] -- retry loop below adjusts T if a row
// ever falls outside (correctness-preserving fallback, never taken here).
#define T_INIT 2.42f

// Skewed LDS index: breaks all power-of-2 stride bank aliasing for the u64
// bitonic accesses (plain layout gives up to 8-way conflicts ~2.9x cost).
__device__ __forceinline__ int PAD(int j) { return j + (j >> 4); }
#define CAP_PAD (CAP + (CAP >> 4))  // 1088 u64 = 8.7 KB

// key = (positive-float logit bits << 32) | (0xFFFFFFFF - flat_idx)
// Sigmoid is monotone, so top-k on logits == top-k on scores; descending
// sort on this key reproduces jax.lax.top_k order (ties: lower index first).
__global__ __launch_bounds__(NTHREADS) void postproc_kernel(
    const float* __restrict__ logits,
    const float4* __restrict__ boxes,
    float* __restrict__ out) {
  const int row = blockIdx.x;
  const int tid = threadIdx.x;

  __shared__ u64 s_keys[CAP_PAD];
  __shared__ int s_cnt;

  const float4* lp = (const float4*)logits + (size_t)row * (QC / 4);

  float T = T_INIT;
  int cnt = 0;
  for (int attempt = 0; attempt < 24; ++attempt) {
    __syncthreads();
    if (tid == 0) s_cnt = 0;
    __syncthreads();
    for (int i = tid; i < QC / 4; i += NTHREADS) {
      float4 v = lp[i];
      float xs[4] = {v.x, v.y, v.z, v.w};
#pragma unroll
      for (int c = 0; c < 4; ++c) {
        float x = xs[c];
        if (x > T) {
          int pos = atomicAdd(&s_cnt, 1);
          if (pos < CAP) {
            u32 idx = (u32)(4 * i + c);
            s_keys[PAD(pos)] =
                ((u64)__float_as_uint(x) << 32) | (u64)(0xFFFFFFFFu - idx);
          }
        }
      }
    }
    __syncthreads();
    cnt = s_cnt;
    if (cnt >= TOPK && cnt <= CAP) break;
    T = (cnt < TOPK) ? (T - 0.55f) : (T + 0.45f);
  }
  if (cnt > CAP) cnt = CAP;

  // pad to CAP with zero keys (sort last under descending order)
  for (int i = cnt + tid; i < CAP; i += NTHREADS) s_keys[PAD(i)] = 0ull;
  __syncthreads();

  // bitonic sort, descending: CAP/2 = 512 compare-exchanges per half-stage.
  // Threads 512..1023 only participate in the barrier.
  for (int size = 2; size <= CAP; size <<= 1) {
    for (int stride = size >> 1; stride > 0; stride >>= 1) {
      if (tid < CAP / 2) {
        int i = tid;
        int lo = 2 * i - (i & (stride - 1));
        int hi = lo + stride;
        int plo = PAD(lo), phi = PAD(hi);
        u64 a = s_keys[plo];
        u64 b = s_keys[phi];
        bool desc = (lo & size) == 0;
        if (desc ? (a < b) : (a > b)) {
          s_keys[plo] = b;
          s_keys[phi] = a;
        }
      }
      __syncthreads();
    }
  }

  // epilogue: threads 0..299 emit one result each
  if (tid < TOPK) {
    const int k = tid;
    float* labels_out = out;                  // [NB, TOPK]
    float* boxes_out = out + NB * TOPK;       // [NB, TOPK, 4]
    float* scores_out = out + NB * TOPK * 5;  // [NB, TOPK]

    float lab = 0.0f, score = 0.0f;
    float4 bo = make_float4(0.0f, 0.0f, 0.0f, 0.0f);
    if (k < cnt) {
      u64 key = s_keys[PAD(k)];
      u32 idx = 0xFFFFFFFFu - (u32)(key & 0xFFFFFFFFull);
      float x = __uint_as_float((u32)(key >> 32));
      int q = (int)(idx / NC);
      int c = (int)(idx - (u32)q * NC);
      lab = (float)c;
      score = (float)(1.0 / (1.0 + exp(-(double)x)));  // exact f32 sigmoid
      float4 bb = boxes[(size_t)row * NQ + q];
      float hw = 0.5f * bb.z, hh = 0.5f * bb.w;
      bo.x = bb.x - hw;
      bo.y = bb.y - hh;
      bo.z = bb.x + hw;
      bo.w = bb.y + hh;
    }
    labels_out[row * TOPK + k] = lab;
    scores_out[row * TOPK + k] = score;
    ((float4*)boxes_out)[row * TOPK + k] = bo;
  }
}

extern "C" void kernel_launch(void* const* d_in, const int* in_sizes, int n_in,
                              void* d_out, int out_size, void* d_ws, size_t ws_size,
                              hipStream_t stream) {
  const float* logits = (const float*)d_in[0];
  const float4* boxes = (const float4*)d_in[1];
  float* out = (float*)d_out;
  postproc_kernel<<<NB, NTHREADS, 0, stream>>>(logits, boxes, out);
}

// Round 4
// 122.679 us; speedup vs baseline: 1.1412x; 1.0696x over previous
//
#include <hip/hip_runtime.h>
#include <math.h>

typedef unsigned long long u64;
typedef unsigned int u32;

#define NB 256       // batch
#define NQ 1000      // queries
#define NC 80        // classes
#define QC 80000     // NQ*NC per row
#define NQ4 (QC / 4) // 20000 float4s per row
#define TOPK 300
#define CAP 512      // candidate capacity = bitonic size (power of 2)
#define NTHREADS 1024

// T=2.585: P(N(0,1) > 2.585) ~ 0.00487 -> ~390 +/- 20 candidates per row.
// 300 is -4.6 sigma, 512 is +6.2 sigma. Bisection fallback below guards
// out-of-window rows (correctness-preserving, never taken on this data).
#define T_INIT 2.585f

__device__ __forceinline__ u64 shfl_xor_u64(u64 v, int mask) {
  int lo = __shfl_xor((int)(u32)(v & 0xFFFFFFFFull), mask, 64);
  int hi = __shfl_xor((int)(u32)(v >> 32), mask, 64);
  return ((u64)(u32)hi << 32) | (u64)(u32)lo;
}

// key = (positive-float logit bits << 32) | (0xFFFFFFFF - flat_idx)
// Sigmoid is monotone => top-k on logits == top-k on scores; descending sort
// on this key reproduces jax.lax.top_k order (ties: lower index first).
__global__ __launch_bounds__(NTHREADS) void postproc_kernel(
    const float* __restrict__ logits,
    const float4* __restrict__ boxes,
    float* __restrict__ out) {
  const int row = blockIdx.x;
  const int tid = threadIdx.x;

  __shared__ u64 s_keys[CAP];
  __shared__ int s_cnt;

  const float4* lp = (const float4*)logits + (size_t)row * NQ4;

  float T = T_INIT;
  float tlo = -1.0f, thi = 7.0f;  // bisection bounds for fallback
  int cnt = 0;

  auto filt = [&](float x, u32 idx) {
    if (x > T) {
      int pos = atomicAdd(&s_cnt, 1);
      if (pos < CAP)
        s_keys[pos] = ((u64)__float_as_uint(x) << 32) | (u64)(0xFFFFFFFFu - idx);
    }
  };

  for (int attempt = 0; attempt < 24; ++attempt) {
    __syncthreads();  // protect s_cnt reset vs. prior-iteration readers
    if (tid == 0) s_cnt = 0;
    __syncthreads();

    // scan: 4x unrolled (16 independent loads' addresses known up front)
    for (int i = tid; i < 16384; i += 4 * NTHREADS) {
      float4 v0 = lp[i];
      float4 v1 = lp[i + NTHREADS];
      float4 v2 = lp[i + 2 * NTHREADS];
      float4 v3 = lp[i + 3 * NTHREADS];
      filt(v0.x, 4 * i);                  filt(v0.y, 4 * i + 1);
      filt(v0.z, 4 * i + 2);              filt(v0.w, 4 * i + 3);
      int i1 = i + NTHREADS;
      filt(v1.x, 4 * i1);                 filt(v1.y, 4 * i1 + 1);
      filt(v1.z, 4 * i1 + 2);             filt(v1.w, 4 * i1 + 3);
      int i2 = i + 2 * NTHREADS;
      filt(v2.x, 4 * i2);                 filt(v2.y, 4 * i2 + 1);
      filt(v2.z, 4 * i2 + 2);             filt(v2.w, 4 * i2 + 3);
      int i3 = i + 3 * NTHREADS;
      filt(v3.x, 4 * i3);                 filt(v3.y, 4 * i3 + 1);
      filt(v3.z, 4 * i3 + 2);             filt(v3.w, 4 * i3 + 3);
    }
    for (int i = 16384 + tid; i < NQ4; i += NTHREADS) {
      float4 v = lp[i];
      filt(v.x, 4 * i);  filt(v.y, 4 * i + 1);
      filt(v.z, 4 * i + 2);  filt(v.w, 4 * i + 3);
    }

    __syncthreads();
    cnt = s_cnt;
    if (cnt >= TOPK && cnt <= CAP) break;
    // bisection: larger T -> fewer candidates
    if (cnt < TOPK) thi = T; else tlo = T;
    T = 0.5f * (tlo + thi);
  }
  if (cnt > CAP) cnt = CAP;

  // ---- register bitonic sort, descending, CAP=512 keys on threads 0..511.
  // Strides <=32: __shfl_xor (no barriers, 39 half-stages).
  // Strides 64/128/256: LDS exchange (6 half-stages, 12 barriers).
  u64 key = 0;
  if (tid < CAP && tid < cnt) key = s_keys[tid];

  for (int k = 2; k <= CAP; k <<= 1) {
    for (int j = k >> 1; j > 0; j >>= 1) {
      if (j >= 64) {
        __syncthreads();
        if (tid < CAP) s_keys[tid] = key;
        __syncthreads();
        if (tid < CAP) {
          u64 other = s_keys[tid ^ j];
          bool iLower = (tid & j) == 0;
          bool dirAsc = (tid & k) != 0;  // k=CAP => all-descending final
          bool keepMin = (dirAsc == iLower);
          key = keepMin ? (key < other ? key : other)
                        : (key > other ? key : other);
        }
      } else if (tid < CAP) {  // wave-uniform branch (tids >=512 whole waves)
        u64 other = shfl_xor_u64(key, j);
        bool iLower = (tid & j) == 0;
        bool dirAsc = (tid & k) != 0;
        bool keepMin = (dirAsc == iLower);
        key = keepMin ? (key < other ? key : other)
                      : (key > other ? key : other);
      }
    }
  }

  // ---- epilogue: thread tid holds the rank-tid key in register
  if (tid < TOPK) {
    float* labels_out = out;                  // [NB, TOPK]
    float* boxes_out = out + NB * TOPK;       // [NB, TOPK, 4]
    float* scores_out = out + NB * TOPK * 5;  // [NB, TOPK]

    float lab = 0.0f, score = 0.0f;
    float4 bo = make_float4(0.0f, 0.0f, 0.0f, 0.0f);
    if (tid < cnt) {
      u32 idx = 0xFFFFFFFFu - (u32)(key & 0xFFFFFFFFull);
      float x = __uint_as_float((u32)(key >> 32));
      int q = (int)(idx / NC);
      int c = (int)(idx - (u32)q * NC);
      lab = (float)c;
      score = (float)(1.0 / (1.0 + exp(-(double)x)));  // exact f32 sigmoid
      float4 bb = boxes[(size_t)row * NQ + q];
      float hw = 0.5f * bb.z, hh = 0.5f * bb.w;
      bo.x = bb.x - hw;
      bo.y = bb.y - hh;
      bo.z = bb.x + hw;
      bo.w = bb.y + hh;
    }
    labels_out[row * TOPK + tid] = lab;
    scores_out[row * TOPK + tid] = score;
    ((float4*)boxes_out)[row * TOPK + tid] = bo;
  }
}

extern "C" void kernel_launch(void* const* d_in, const int* in_sizes, int n_in,
                              void* d_out, int out_size, void* d_ws, size_t ws_size,
                              hipStream_t stream) {
  const float* logits = (const float*)d_in[0];
  const float4* boxes = (const float4*)d_in[1];
  float* out = (float*)d_out;
  postproc_kernel<<<NB, NTHREADS, 0, stream>>>(logits, boxes, out);
}